// Round 5
// baseline (1121.091 us; speedup 1.0000x reference)
//
#include <hip/hip_runtime.h>

#define NBATCH 2048

typedef __attribute__((ext_vector_type(8))) short short8;
typedef __attribute__((ext_vector_type(4))) short short4v;
typedef __attribute__((ext_vector_type(4))) float f32x4;
typedef __attribute__((ext_vector_type(4))) unsigned short us4;

__device__ __forceinline__ unsigned short f2bf(float f) {
    unsigned int u = __float_as_uint(f);
    u += 0x7FFFu + ((u >> 16) & 1u);
    return (unsigned short)(u >> 16);
}

__device__ __forceinline__ short4v pack4(f32x4 v) {
    short4v r;
    r[0] = (short)f2bf(v[0]); r[1] = (short)f2bf(v[1]);
    r[2] = (short)f2bf(v[2]); r[3] = (short)f2bf(v[3]);
    return r;
}
__device__ __forceinline__ short8 pack8(f32x4 lo, f32x4 hi) {
    short8 r;
    r[0] = (short)f2bf(lo[0]); r[1] = (short)f2bf(lo[1]);
    r[2] = (short)f2bf(lo[2]); r[3] = (short)f2bf(lo[3]);
    r[4] = (short)f2bf(hi[0]); r[5] = (short)f2bf(hi[1]);
    r[6] = (short)f2bf(hi[2]); r[7] = (short)f2bf(hi[3]);
    return r;
}

__device__ __forceinline__ f32x4 mfma16(short4v a, short4v b, f32x4 c) {
#if __has_builtin(__builtin_amdgcn_mfma_f32_16x16x16bf16_1k)
    return __builtin_amdgcn_mfma_f32_16x16x16bf16_1k(a, b, c, 0, 0, 0);
#elif __has_builtin(__builtin_amdgcn_mfma_f32_16x16x16_bf16)
    return __builtin_amdgcn_mfma_f32_16x16x16_bf16(a, b, c, 0, 0, 0);
#else
    asm volatile("v_mfma_f32_16x16x16_bf16 %0, %1, %2, %0" : "+v"(c) : "v"(a), "v"(b));
    return c;
#endif
}
#define MFMA32(a, b, c) __builtin_amdgcn_mfma_f32_16x16x32_bf16(a, b, c, 0, 0, 0)

#define SW(t) ((((t) ^ ((t) >> 3)) & 7) << 4)

// ws layout (bytes)
#define IW_OFF    0u        // (unused slot, kept for layout stability)
#define PMW_OFF   8192u     // (pm_w + I) bf16 [4][64][64]
#define THW_OFF   40960u    // [256][512] bf16
#define PHW_OFF   303104u   // [256][512] bf16
#define GW_OFF    565248u   // [256][512] bf16
#define OUTW_OFF  827392u   // [512][256] bf16 (BN-scaled)
#define OUTB_OFF  1089536u  // [512] f32 (folded BN bias)
#define WS_BYTES  1091584u

__global__ void prep_kernel(const float* __restrict__ pm_w, const float* __restrict__ g_w,
                            const float* __restrict__ th_w, const float* __restrict__ ph_w,
                            const float* __restrict__ out_w, const float* __restrict__ gamma,
                            const float* __restrict__ beta, const float* __restrict__ mean,
                            const float* __restrict__ var, char* __restrict__ ws) {
    int i = blockIdx.x * 256 + threadIdx.x;
    unsigned short* iw  = (unsigned short*)(ws + IW_OFF);
    unsigned short* pmw = (unsigned short*)(ws + PMW_OFF);
    unsigned short* thw = (unsigned short*)(ws + THW_OFF);
    unsigned short* phw = (unsigned short*)(ws + PHW_OFF);
    unsigned short* gww = (unsigned short*)(ws + GW_OFF);
    unsigned short* oww = (unsigned short*)(ws + OUTW_OFF);
    float* ob = (float*)(ws + OUTB_OFF);
    if (i < 4096) iw[i] = f2bf(((i >> 6) == (i & 63)) ? 1.0f : 0.0f);
    if (i < 16384) {
        float ident = (((i >> 6) & 63) == (i & 63)) ? 1.0f : 0.0f;
        pmw[i] = f2bf(pm_w[i] + ident);
    }
    if (i < 131072) {
        thw[i] = f2bf(th_w[i]);
        phw[i] = f2bf(ph_w[i]);
        gww[i] = f2bf(g_w[i]);
        int o = i >> 8;
        float inv = gamma[o] * rsqrtf(var[o] + 1e-5f);
        oww[i] = f2bf(out_w[i] * inv);
    }
    if (i < 512) {
        float inv = gamma[i] * rsqrtf(var[i] + 1e-5f);
        ob[i] = beta[i] - mean[i] * inv;
    }
}

// One batch per block, 8 waves (wave = (head, nq-half)). 64KB LDS:
//   FR = ctx' as MFMA32 frag-array: [c32-tile 16][m16-tile 4] x 1024B
//        (lane*16B holds n=l15-token, k=c l4*8+0..7 -- ds_read_b128 uniform)
//   after T4 barrier: first 32KB reused for Y^T[64][256] bf16 (SW-swizzled).
// q^T never staged: identity-MFMA transposes q tiles into Theta's B-frags.
// Residual for posmix folded into (pm_w + I) by prep.
// launch_bounds(512,2): 256-reg V+A cap -- spill-free is priority #1 (R2/R4
// both lost >2x to scratch traffic under the (512,4) 128-reg cap).
__global__ __launch_bounds__(512, 2)
void lawin_main(const float* __restrict__ query, const float* __restrict__ context,
                const float* __restrict__ pm_b, const float* __restrict__ th_b,
                const float* __restrict__ ph_b, const float* __restrict__ g_b,
                const char* __restrict__ ws, float* __restrict__ out) {
    __shared__ __align__(16) char FR[65536];

    const char* pmw = ws + PMW_OFF;
    const char* thw = ws + THW_OFF;
    const char* phw = ws + PHW_OFF;
    const char* gww = ws + GW_OFF;
    const char* oww = ws + OUTW_OFF;
    const float* ob = (const float*)(ws + OUTB_OFF);

    const int b = blockIdx.x;
    const int tid = threadIdx.x;
    const int wid = tid >> 6;
    const int lane = tid & 63;
    const int l15 = lane & 15;
    const int l4 = lane >> 4;
    const int h = wid >> 1;
    const int half = wid & 1;
    const int nqbase = half * 32;

    const float* qb = query + (size_t)b * 32768;
    const float* cbp = context + (size_t)b * 32768;
    float* outb = out + (size_t)b * 32768;

    // per-lane identity B-frag for the transpose MFMA (I[t][t'])
    short4v idf;
    #pragma unroll
    for (int i = 0; i < 4; ++i) idf[i] = (short)((l4 * 4 + i == l15) ? 0x3F80 : 0);
    const f32x4 fzero = {0.f, 0.f, 0.f, 0.f};

    // ---------- T1: Theta[d][nq] via identity-transpose chains (global q, no LDS) ----------
    short4v thB[4][2];   // [d16-tile][nq16-tile] as S-mfma B-frags
    {
        f32x4 acc[4][2] = {};
        #pragma unroll 4
        for (int ks = 0; ks < 32; ++ks) {      // c 16-tiles
            short4v qtB[2];
            #pragma unroll
            for (int tt = 0; tt < 2; ++tt) {
                f32x4 qv = *(const f32x4*)(qb + (ks * 16 + l15) * 64 + nqbase + tt * 16 + l4 * 4);
                f32x4 d = mfma16(pack4(qv), idf, fzero);   // D[c][t] = q chunk transposed
                qtB[tt] = pack4(d);
            }
            #pragma unroll
            for (int td = 0; td < 4; ++td) {
                short4v aw = *(const short4v*)(thw + (h * 64 + td * 16 + l15) * 1024 + ks * 32 + l4 * 8);
                #pragma unroll
                for (int tt = 0; tt < 2; ++tt)
                    acc[td][tt] = mfma16(aw, qtB[tt], acc[td][tt]);
            }
        }
        #pragma unroll
        for (int td = 0; td < 4; ++td) {
            f32x4 bv = *(const f32x4*)(th_b + h * 64 + td * 16 + l4 * 4);
            #pragma unroll
            for (int tt = 0; tt < 2; ++tt)
                thB[td][tt] = pack4(acc[td][tt] + bv);
        }
    }

    // ---------- T2: posmix (residual folded into W+I), write ctx' frag-array ----------
    {
        const int cb0 = wid * 64;
        #pragma unroll 1
        for (int mth = 0; mth < 2; ++mth) {
            f32x4 acc[4][2] = {};
            #pragma unroll
            for (int ks = 0; ks < 2; ++ks) {
                short8 a[4], bb[2];
                #pragma unroll
                for (int ct = 0; ct < 4; ++ct) {
                    const float* p = cbp + (cb0 + ct * 16 + l15) * 64 + ks * 32 + l4 * 8;
                    a[ct] = pack8(*(const f32x4*)p, *(const f32x4*)(p + 4));
                }
                #pragma unroll
                for (int mt2 = 0; mt2 < 2; ++mt2)
                    bb[mt2] = *(const short8*)(pmw + (h * 64 + mth * 32 + mt2 * 16 + l15) * 128 + ks * 64 + l4 * 16);
                #pragma unroll
                for (int ct = 0; ct < 4; ++ct)
                    #pragma unroll
                    for (int mt2 = 0; mt2 < 2; ++mt2)
                        acc[ct][mt2] = MFMA32(a[ct], bb[mt2], acc[ct][mt2]);
            }
            #pragma unroll
            for (int ct = 0; ct < 4; ++ct)
                #pragma unroll
                for (int mt2 = 0; mt2 < 2; ++mt2) {
                    float pbv = pm_b[h * 64 + mth * 32 + mt2 * 16 + l15];
                    us4 pk;
                    f32x4 v = acc[ct][mt2] + pbv;
                    pk[0] = f2bf(v[0]); pk[1] = f2bf(v[1]); pk[2] = f2bf(v[2]); pk[3] = f2bf(v[3]);
                    const int c32 = wid * 2 + (ct >> 1);
                    const int mt = mth * 2 + mt2;
                    const int lanep = ((ct & 1) * 2 + (l4 >> 1)) * 16 + l15;
                    *(us4*)(FR + (c32 * 4 + mt) * 1024 + lanep * 16 + (l4 & 1) * 8) = pk;
                }
        }
    }
    __syncthreads();

    // ---------- T3: Phi -> S^T -> softmax -> pB ----------
    short4v pB[4][2];    // [nc16-tile][nq16-tile] PV A-frags
    {
        f32x4 s_acc[4][2] = {};   // S^T tiles: row=nc(l4*4+r), col=nq(l15)
        #pragma unroll 1
        for (int dh = 0; dh < 2; ++dh) {
            #pragma unroll 1
            for (int tch = 0; tch < 2; ++tch) {
                f32x4 pacc[2][2] = {};   // Phi D[d][nc]: [td2][tc2]
                #pragma unroll 2
                for (int ks = 0; ks < 16; ++ks) {   // c 32-tiles
                    short8 a[2], bb[2];
                    #pragma unroll
                    for (int td2 = 0; td2 < 2; ++td2)
                        a[td2] = *(const short8*)(phw + (h * 64 + dh * 32 + td2 * 16 + l15) * 1024 + ks * 64 + l4 * 16);
                    #pragma unroll
                    for (int tc2 = 0; tc2 < 2; ++tc2)
                        bb[tc2] = *(const short8*)(FR + (ks * 4 + tch * 2 + tc2) * 1024 + lane * 16);
                    #pragma unroll
                    for (int td2 = 0; td2 < 2; ++td2)
                        #pragma unroll
                        for (int tc2 = 0; tc2 < 2; ++tc2)
                            pacc[td2][tc2] = MFMA32(a[td2], bb[tc2], pacc[td2][tc2]);
                }
                #pragma unroll
                for (int td2 = 0; td2 < 2; ++td2) {
                    f32x4 bv = *(const f32x4*)(ph_b + h * 64 + dh * 32 + td2 * 16 + l4 * 4);
                    #pragma unroll
                    for (int tc2 = 0; tc2 < 2; ++tc2) {
                        short4v phB = pack4(pacc[td2][tc2] + bv);
                        #pragma unroll
                        for (int tb = 0; tb < 2; ++tb)
                            s_acc[tch * 2 + tc2][tb] = mfma16(phB, thB[dh * 2 + td2][tb], s_acc[tch * 2 + tc2][tb]);
                    }
                }
            }
        }
        // softmax over nc (row dim: per-lane 16 values + shfl over l4), scale 1/8
        #pragma unroll
        for (int tb = 0; tb < 2; ++tb) {
            float mx = -1e30f;
            #pragma unroll
            for (int tc = 0; tc < 4; ++tc)
                #pragma unroll
                for (int r = 0; r < 4; ++r) mx = fmaxf(mx, s_acc[tc][tb][r]);
            mx = fmaxf(mx, __shfl_xor(mx, 16));
            mx = fmaxf(mx, __shfl_xor(mx, 32));
            float sum = 0.f;
            #pragma unroll
            for (int tc = 0; tc < 4; ++tc)
                #pragma unroll
                for (int r = 0; r < 4; ++r) {
                    float v = __expf((s_acc[tc][tb][r] - mx) * 0.125f);
                    s_acc[tc][tb][r] = v;
                    sum += v;
                }
            sum += __shfl_xor(sum, 16);
            sum += __shfl_xor(sum, 32);
            float rinv = 1.0f / sum;
            #pragma unroll
            for (int tc = 0; tc < 4; ++tc)
                pB[tc][tb] = pack4(s_acc[tc][tb] * rinv);
        }
    }

    // ---------- T4: G^T and PV chain -> y_acc ----------
    f32x4 y_acc[2][4] = {};    // [nq-tile][dg16-tile], row=nq, col=dg
    #pragma unroll 1
    for (int gh = 0; gh < 2; ++gh) {
        #pragma unroll 1
        for (int tnch = 0; tnch < 2; ++tnch) {
            f32x4 gacc[2][2] = {};   // G D[nc][dg]: [tn][tg]
            #pragma unroll 2
            for (int ks = 0; ks < 16; ++ks) {
                short8 a[2], bb[2];
                #pragma unroll
                for (int tn = 0; tn < 2; ++tn)
                    a[tn] = *(const short8*)(FR + (ks * 4 + tnch * 2 + tn) * 1024 + lane * 16);
                #pragma unroll
                for (int tg = 0; tg < 2; ++tg)
                    bb[tg] = *(const short8*)(gww + (h * 64 + gh * 32 + tg * 16 + l15) * 1024 + ks * 64 + l4 * 16);
                #pragma unroll
                for (int tn = 0; tn < 2; ++tn)
                    #pragma unroll
                    for (int tg = 0; tg < 2; ++tg)
                        gacc[tn][tg] = MFMA32(a[tn], bb[tg], gacc[tn][tg]);
            }
            #pragma unroll
            for (int tg = 0; tg < 2; ++tg) {
                float gbv = g_b[h * 64 + gh * 32 + tg * 16 + l15];
                #pragma unroll
                for (int tn = 0; tn < 2; ++tn) {
                    short4v gB = pack4(gacc[tn][tg] + gbv);
                    #pragma unroll
                    for (int tb = 0; tb < 2; ++tb)
                        y_acc[tb][gh * 2 + tg] = mfma16(pB[tnch * 2 + tn][tb], gB, y_acc[tb][gh * 2 + tg]);
                }
            }
        }
    }
    __syncthreads();   // all waves done reading ctx' frags

    // ---------- Y^T bf16 [64][256] (SW-swizzled) -> FR[0:32K) ----------
    #pragma unroll
    for (int tb = 0; tb < 2; ++tb)
        #pragma unroll
        for (int tdg = 0; tdg < 4; ++tdg)
            #pragma unroll
            for (int r = 0; r < 4; ++r) {
                int nq = nqbase + tb * 16 + l4 * 4 + r;
                int dg = h * 64 + tdg * 16 + l15;
                *(unsigned short*)(FR + nq * 512 + ((2 * dg) ^ SW(nq))) = f2bf(y_acc[tb][tdg][r]);
            }
    __syncthreads();

    // ---------- T5: out-proj (BN folded) + bias + f32 query residual ----------
    #pragma unroll 1
    for (int och = 0; och < 2; ++och) {
        const int ob0 = wid * 64 + och * 32;
        f32x4 acc[4][2] = {};
        #pragma unroll 2
        for (int ks = 0; ks < 8; ++ks) {
            const int kb = ks * 64 + l4 * 16;
            short8 a[4], bb[2];
            #pragma unroll
            for (int tr = 0; tr < 4; ++tr) {
                int tok = tr * 16 + l15;
                a[tr] = *(const short8*)(FR + tok * 512 + (kb ^ SW(tok)));
            }
            #pragma unroll
            for (int oc = 0; oc < 2; ++oc)
                bb[oc] = *(const short8*)(oww + (ob0 + oc * 16 + l15) * 512 + kb);
            #pragma unroll
            for (int tr = 0; tr < 4; ++tr)
                #pragma unroll
                for (int oc = 0; oc < 2; ++oc)
                    acc[tr][oc] = MFMA32(a[tr], bb[oc], acc[tr][oc]);
        }
        #pragma unroll
        for (int oc = 0; oc < 2; ++oc) {
            const int o = ob0 + oc * 16 + l15;
            const float bias = ob[o];
            #pragma unroll
            for (int tr = 0; tr < 4; ++tr) {
                const int tt = tr * 16 + l4 * 4;
                f32x4 qv = *(const f32x4*)(qb + o * 64 + tt);
                f32x4 ov;
                #pragma unroll
                for (int r = 0; r < 4; ++r) ov[r] = acc[tr][oc][r] + bias + qv[r];
                *(f32x4*)(outb + o * 64 + tt) = ov;
            }
        }
    }
}

extern "C" void kernel_launch(void* const* d_in, const int* in_sizes, int n_in,
                              void* d_out, int out_size, void* d_ws, size_t ws_size,
                              hipStream_t stream) {
    const float* query   = (const float*)d_in[0];
    const float* context = (const float*)d_in[1];
    const float* pm_w    = (const float*)d_in[2];
    const float* pm_b    = (const float*)d_in[3];
    const float* g_w     = (const float*)d_in[4];
    const float* g_b     = (const float*)d_in[5];
    const float* th_w    = (const float*)d_in[6];
    const float* th_b    = (const float*)d_in[7];
    const float* ph_w    = (const float*)d_in[8];
    const float* ph_b    = (const float*)d_in[9];
    const float* out_w   = (const float*)d_in[10];
    const float* gamma   = (const float*)d_in[11];
    const float* beta    = (const float*)d_in[12];
    const float* mean    = (const float*)d_in[13];
    const float* var     = (const float*)d_in[14];
    char* ws = (char*)d_ws;
    float* out = (float*)d_out;

    if (ws_size < WS_BYTES) return;

    prep_kernel<<<512, 256, 0, stream>>>(pm_w, g_w, th_w, ph_w, out_w, gamma, beta, mean, var, ws);
    lawin_main<<<NBATCH, 512, 0, stream>>>(query, context, pm_b, th_b, ph_b, g_b, ws, out);
}

// Round 6
// 975.445 us; speedup vs baseline: 1.1493x; 1.1493x over previous
//
#include <hip/hip_runtime.h>

#define NBATCH 2048

typedef __attribute__((ext_vector_type(8))) short short8;
typedef __attribute__((ext_vector_type(4))) short short4v;
typedef __attribute__((ext_vector_type(4))) float f32x4;
typedef __attribute__((ext_vector_type(4))) unsigned short us4;

__device__ __forceinline__ unsigned short f2bf(float f) {
    unsigned int u = __float_as_uint(f);
    u += 0x7FFFu + ((u >> 16) & 1u);
    return (unsigned short)(u >> 16);
}

__device__ __forceinline__ short4v pack4(f32x4 v) {
    short4v r;
    r[0] = (short)f2bf(v[0]); r[1] = (short)f2bf(v[1]);
    r[2] = (short)f2bf(v[2]); r[3] = (short)f2bf(v[3]);
    return r;
}
__device__ __forceinline__ short8 pack8(f32x4 lo, f32x4 hi) {
    short8 r;
    r[0] = (short)f2bf(lo[0]); r[1] = (short)f2bf(lo[1]);
    r[2] = (short)f2bf(lo[2]); r[3] = (short)f2bf(lo[3]);
    r[4] = (short)f2bf(hi[0]); r[5] = (short)f2bf(hi[1]);
    r[6] = (short)f2bf(hi[2]); r[7] = (short)f2bf(hi[3]);
    return r;
}

__device__ __forceinline__ f32x4 mfma16(short4v a, short4v b, f32x4 c) {
#if __has_builtin(__builtin_amdgcn_mfma_f32_16x16x16bf16_1k)
    return __builtin_amdgcn_mfma_f32_16x16x16bf16_1k(a, b, c, 0, 0, 0);
#elif __has_builtin(__builtin_amdgcn_mfma_f32_16x16x16_bf16)
    return __builtin_amdgcn_mfma_f32_16x16x16_bf16(a, b, c, 0, 0, 0);
#else
    asm volatile("v_mfma_f32_16x16x16_bf16 %0, %1, %2, %0" : "+v"(c) : "v"(a), "v"(b));
    return c;
#endif
}
#define MFMA32(a, b, c) __builtin_amdgcn_mfma_f32_16x16x32_bf16(a, b, c, 0, 0, 0)

#define SW(t) ((((t) ^ ((t) >> 3)) & 7) << 4)

// ws layout (bytes)
#define IW_OFF    0u        // (unused slot, kept for layout stability)
#define PMW_OFF   8192u     // (pm_w + I) bf16 [4][64][64]
#define THW_OFF   40960u    // [256][512] bf16
#define PHW_OFF   303104u   // [256][512] bf16
#define GW_OFF    565248u   // [256][512] bf16
#define OUTW_OFF  827392u   // [512][256] bf16 (BN-scaled)
#define OUTB_OFF  1089536u  // [512] f32 (folded BN bias)
#define WS_BYTES  1091584u

__global__ void prep_kernel(const float* __restrict__ pm_w, const float* __restrict__ g_w,
                            const float* __restrict__ th_w, const float* __restrict__ ph_w,
                            const float* __restrict__ out_w, const float* __restrict__ gamma,
                            const float* __restrict__ beta, const float* __restrict__ mean,
                            const float* __restrict__ var, char* __restrict__ ws) {
    int i = blockIdx.x * 256 + threadIdx.x;
    unsigned short* iw  = (unsigned short*)(ws + IW_OFF);
    unsigned short* pmw = (unsigned short*)(ws + PMW_OFF);
    unsigned short* thw = (unsigned short*)(ws + THW_OFF);
    unsigned short* phw = (unsigned short*)(ws + PHW_OFF);
    unsigned short* gww = (unsigned short*)(ws + GW_OFF);
    unsigned short* oww = (unsigned short*)(ws + OUTW_OFF);
    float* ob = (float*)(ws + OUTB_OFF);
    if (i < 4096) iw[i] = f2bf(((i >> 6) == (i & 63)) ? 1.0f : 0.0f);
    if (i < 16384) {
        float ident = (((i >> 6) & 63) == (i & 63)) ? 1.0f : 0.0f;
        pmw[i] = f2bf(pm_w[i] + ident);
    }
    if (i < 131072) {
        thw[i] = f2bf(th_w[i]);
        phw[i] = f2bf(ph_w[i]);
        gww[i] = f2bf(g_w[i]);
        int o = i >> 8;
        float inv = gamma[o] * rsqrtf(var[o] + 1e-5f);
        oww[i] = f2bf(out_w[i] * inv);
    }
    if (i < 512) {
        float inv = gamma[i] * rsqrtf(var[i] + 1e-5f);
        ob[i] = beta[i] - mean[i] * inv;
    }
}

// One batch per block, 8 waves (wave = (head, nq-half)). 64KB LDS:
//   FR = ctx' as MFMA32 frag-array: [c32-tile 16][m16-tile 4] x 1024B
//   after T4 barrier: first 32KB reused for Y^T[64][256] bf16 (SW-swizzled).
// q^T never staged: identity-MFMA transposes q tiles into Theta's B-frags.
// Residual for posmix folded into (pm_w + I) by prep.
// CRITICAL (rule #20): every phase loop whose index feeds a register-array
// subscript (dh/tch/gh/tnch) is FULLY unrolled -- runtime-indexed
// ext_vector arrays go to scratch regardless of register budget (R4/R5:
// ~720MB scratch writes, VGPR=60). ks loops only feed addresses -> partial
// unroll is safe.
__global__ __launch_bounds__(512, 4)
void lawin_main(const float* __restrict__ query, const float* __restrict__ context,
                const float* __restrict__ pm_b, const float* __restrict__ th_b,
                const float* __restrict__ ph_b, const float* __restrict__ g_b,
                const char* __restrict__ ws, float* __restrict__ out) {
    __shared__ __align__(16) char FR[65536];

    const char* pmw = ws + PMW_OFF;
    const char* thw = ws + THW_OFF;
    const char* phw = ws + PHW_OFF;
    const char* gww = ws + GW_OFF;
    const char* oww = ws + OUTW_OFF;
    const float* ob = (const float*)(ws + OUTB_OFF);

    const int b = blockIdx.x;
    const int tid = threadIdx.x;
    const int wid = tid >> 6;
    const int lane = tid & 63;
    const int l15 = lane & 15;
    const int l4 = lane >> 4;
    const int h = wid >> 1;
    const int half = wid & 1;
    const int nqbase = half * 32;

    const float* qb = query + (size_t)b * 32768;
    const float* cbp = context + (size_t)b * 32768;
    float* outb = out + (size_t)b * 32768;

    // per-lane identity B-frag for the transpose MFMA (I[t][t'])
    short4v idf;
    #pragma unroll
    for (int i = 0; i < 4; ++i) idf[i] = (short)((l4 * 4 + i == l15) ? 0x3F80 : 0);
    const f32x4 fzero = {0.f, 0.f, 0.f, 0.f};

    // ---------- T1: Theta[d][nq] via identity-transpose chains (global q, no LDS) ----------
    short4v thB[4][2];   // [d16-tile][nq16-tile] as S-mfma B-frags
    {
        f32x4 acc[4][2] = {};
        #pragma unroll 4
        for (int ks = 0; ks < 32; ++ks) {      // c 16-tiles
            short4v qtB[2];
            #pragma unroll
            for (int tt = 0; tt < 2; ++tt) {
                f32x4 qv = *(const f32x4*)(qb + (ks * 16 + l15) * 64 + nqbase + tt * 16 + l4 * 4);
                f32x4 d = mfma16(pack4(qv), idf, fzero);   // D[c][t] = q chunk transposed
                qtB[tt] = pack4(d);
            }
            #pragma unroll
            for (int td = 0; td < 4; ++td) {
                short4v aw = *(const short4v*)(thw + (h * 64 + td * 16 + l15) * 1024 + ks * 32 + l4 * 8);
                #pragma unroll
                for (int tt = 0; tt < 2; ++tt)
                    acc[td][tt] = mfma16(aw, qtB[tt], acc[td][tt]);
            }
        }
        #pragma unroll
        for (int td = 0; td < 4; ++td) {
            f32x4 bv = *(const f32x4*)(th_b + h * 64 + td * 16 + l4 * 4);
            #pragma unroll
            for (int tt = 0; tt < 2; ++tt)
                thB[td][tt] = pack4(acc[td][tt] + bv);
        }
    }

    // ---------- T2: posmix (residual folded into W+I), write ctx' frag-array ----------
    {
        const int cb0 = wid * 64;
        #pragma unroll 1
        for (int mth = 0; mth < 2; ++mth) {    // mth only feeds addresses; acc local per iter
            f32x4 acc[4][2] = {};
            #pragma unroll
            for (int ks = 0; ks < 2; ++ks) {
                short8 a[4], bb[2];
                #pragma unroll
                for (int ct = 0; ct < 4; ++ct) {
                    const float* p = cbp + (cb0 + ct * 16 + l15) * 64 + ks * 32 + l4 * 8;
                    a[ct] = pack8(*(const f32x4*)p, *(const f32x4*)(p + 4));
                }
                #pragma unroll
                for (int mt2 = 0; mt2 < 2; ++mt2)
                    bb[mt2] = *(const short8*)(pmw + (h * 64 + mth * 32 + mt2 * 16 + l15) * 128 + ks * 64 + l4 * 16);
                #pragma unroll
                for (int ct = 0; ct < 4; ++ct)
                    #pragma unroll
                    for (int mt2 = 0; mt2 < 2; ++mt2)
                        acc[ct][mt2] = MFMA32(a[ct], bb[mt2], acc[ct][mt2]);
            }
            #pragma unroll
            for (int ct = 0; ct < 4; ++ct)
                #pragma unroll
                for (int mt2 = 0; mt2 < 2; ++mt2) {
                    float pbv = pm_b[h * 64 + mth * 32 + mt2 * 16 + l15];
                    us4 pk;
                    f32x4 v = acc[ct][mt2] + pbv;
                    pk[0] = f2bf(v[0]); pk[1] = f2bf(v[1]); pk[2] = f2bf(v[2]); pk[3] = f2bf(v[3]);
                    const int c32 = wid * 2 + (ct >> 1);
                    const int mt = mth * 2 + mt2;
                    const int lanep = ((ct & 1) * 2 + (l4 >> 1)) * 16 + l15;
                    *(us4*)(FR + (c32 * 4 + mt) * 1024 + lanep * 16 + (l4 & 1) * 8) = pk;
                }
        }
    }
    __syncthreads();

    // ---------- T3: Phi -> S^T -> softmax -> pB ----------
    short4v pB[4][2];    // [nc16-tile][nq16-tile] PV A-frags
    {
        f32x4 s_acc[4][2] = {};   // S^T tiles: row=nc(l4*4+r), col=nq(l15)
        #pragma unroll
        for (int dh = 0; dh < 2; ++dh) {          // FULL unroll: indexes thB
            #pragma unroll
            for (int tch = 0; tch < 2; ++tch) {   // FULL unroll: indexes s_acc
                f32x4 pacc[2][2] = {};   // Phi D[d][nc]: [td2][tc2]
                #pragma unroll 2
                for (int ks = 0; ks < 16; ++ks) {   // c 32-tiles
                    short8 a[2], bb[2];
                    #pragma unroll
                    for (int td2 = 0; td2 < 2; ++td2)
                        a[td2] = *(const short8*)(phw + (h * 64 + dh * 32 + td2 * 16 + l15) * 1024 + ks * 64 + l4 * 16);
                    #pragma unroll
                    for (int tc2 = 0; tc2 < 2; ++tc2)
                        bb[tc2] = *(const short8*)(FR + (ks * 4 + tch * 2 + tc2) * 1024 + lane * 16);
                    #pragma unroll
                    for (int td2 = 0; td2 < 2; ++td2)
                        #pragma unroll
                        for (int tc2 = 0; tc2 < 2; ++tc2)
                            pacc[td2][tc2] = MFMA32(a[td2], bb[tc2], pacc[td2][tc2]);
                }
                #pragma unroll
                for (int td2 = 0; td2 < 2; ++td2) {
                    f32x4 bv = *(const f32x4*)(ph_b + h * 64 + dh * 32 + td2 * 16 + l4 * 4);
                    #pragma unroll
                    for (int tc2 = 0; tc2 < 2; ++tc2) {
                        short4v phB = pack4(pacc[td2][tc2] + bv);
                        #pragma unroll
                        for (int tb = 0; tb < 2; ++tb)
                            s_acc[tch * 2 + tc2][tb] = mfma16(phB, thB[dh * 2 + td2][tb], s_acc[tch * 2 + tc2][tb]);
                    }
                }
            }
        }
        // softmax over nc (row dim: per-lane 16 values + shfl over l4), scale 1/8
        #pragma unroll
        for (int tb = 0; tb < 2; ++tb) {
            float mx = -1e30f;
            #pragma unroll
            for (int tc = 0; tc < 4; ++tc)
                #pragma unroll
                for (int r = 0; r < 4; ++r) mx = fmaxf(mx, s_acc[tc][tb][r]);
            mx = fmaxf(mx, __shfl_xor(mx, 16));
            mx = fmaxf(mx, __shfl_xor(mx, 32));
            float sum = 0.f;
            #pragma unroll
            for (int tc = 0; tc < 4; ++tc)
                #pragma unroll
                for (int r = 0; r < 4; ++r) {
                    float v = __expf((s_acc[tc][tb][r] - mx) * 0.125f);
                    s_acc[tc][tb][r] = v;
                    sum += v;
                }
            sum += __shfl_xor(sum, 16);
            sum += __shfl_xor(sum, 32);
            float rinv = 1.0f / sum;
            #pragma unroll
            for (int tc = 0; tc < 4; ++tc)
                pB[tc][tb] = pack4(s_acc[tc][tb] * rinv);
        }
    }

    // ---------- T4: G^T and PV chain -> y_acc ----------
    f32x4 y_acc[2][4] = {};    // [nq-tile][dg16-tile], row=nq, col=dg
    #pragma unroll
    for (int gh = 0; gh < 2; ++gh) {              // FULL unroll: indexes y_acc
        #pragma unroll
        for (int tnch = 0; tnch < 2; ++tnch) {    // FULL unroll: indexes pB
            f32x4 gacc[2][2] = {};   // G D[nc][dg]: [tn][tg]
            #pragma unroll 2
            for (int ks = 0; ks < 16; ++ks) {
                short8 a[2], bb[2];
                #pragma unroll
                for (int tn = 0; tn < 2; ++tn)
                    a[tn] = *(const short8*)(FR + (ks * 4 + tnch * 2 + tn) * 1024 + lane * 16);
                #pragma unroll
                for (int tg = 0; tg < 2; ++tg)
                    bb[tg] = *(const short8*)(gww + (h * 64 + gh * 32 + tg * 16 + l15) * 1024 + ks * 64 + l4 * 16);
                #pragma unroll
                for (int tn = 0; tn < 2; ++tn)
                    #pragma unroll
                    for (int tg = 0; tg < 2; ++tg)
                        gacc[tn][tg] = MFMA32(a[tn], bb[tg], gacc[tn][tg]);
            }
            #pragma unroll
            for (int tg = 0; tg < 2; ++tg) {
                float gbv = g_b[h * 64 + gh * 32 + tg * 16 + l15];
                #pragma unroll
                for (int tn = 0; tn < 2; ++tn) {
                    short4v gB = pack4(gacc[tn][tg] + gbv);
                    #pragma unroll
                    for (int tb = 0; tb < 2; ++tb)
                        y_acc[tb][gh * 2 + tg] = mfma16(pB[tnch * 2 + tn][tb], gB, y_acc[tb][gh * 2 + tg]);
                }
            }
        }
    }
    __syncthreads();   // all waves done reading ctx' frags

    // ---------- Y^T bf16 [64][256] (SW-swizzled) -> FR[0:32K) ----------
    #pragma unroll
    for (int tb = 0; tb < 2; ++tb)
        #pragma unroll
        for (int tdg = 0; tdg < 4; ++tdg)
            #pragma unroll
            for (int r = 0; r < 4; ++r) {
                int nq = nqbase + tb * 16 + l4 * 4 + r;
                int dg = h * 64 + tdg * 16 + l15;
                *(unsigned short*)(FR + nq * 512 + ((2 * dg) ^ SW(nq))) = f2bf(y_acc[tb][tdg][r]);
            }
    __syncthreads();

    // ---------- T5: out-proj (BN folded) + bias + f32 query residual ----------
    #pragma unroll 1
    for (int och = 0; och < 2; ++och) {    // och only feeds addresses; acc local per iter
        const int ob0 = wid * 64 + och * 32;
        f32x4 acc[4][2] = {};
        #pragma unroll 2
        for (int ks = 0; ks < 8; ++ks) {
            const int kb = ks * 64 + l4 * 16;
            short8 a[4], bb[2];
            #pragma unroll
            for (int tr = 0; tr < 4; ++tr) {
                int tok = tr * 16 + l15;
                a[tr] = *(const short8*)(FR + tok * 512 + (kb ^ SW(tok)));
            }
            #pragma unroll
            for (int oc = 0; oc < 2; ++oc)
                bb[oc] = *(const short8*)(oww + (ob0 + oc * 16 + l15) * 512 + kb);
            #pragma unroll
            for (int tr = 0; tr < 4; ++tr)
                #pragma unroll
                for (int oc = 0; oc < 2; ++oc)
                    acc[tr][oc] = MFMA32(a[tr], bb[oc], acc[tr][oc]);
        }
        #pragma unroll
        for (int oc = 0; oc < 2; ++oc) {
            const int o = ob0 + oc * 16 + l15;
            const float bias = ob[o];
            #pragma unroll
            for (int tr = 0; tr < 4; ++tr) {
                const int tt = tr * 16 + l4 * 4;
                f32x4 qv = *(const f32x4*)(qb + o * 64 + tt);
                f32x4 ov;
                #pragma unroll
                for (int r = 0; r < 4; ++r) ov[r] = acc[tr][oc][r] + bias + qv[r];
                *(f32x4*)(outb + o * 64 + tt) = ov;
            }
        }
    }
}

extern "C" void kernel_launch(void* const* d_in, const int* in_sizes, int n_in,
                              void* d_out, int out_size, void* d_ws, size_t ws_size,
                              hipStream_t stream) {
    const float* query   = (const float*)d_in[0];
    const float* context = (const float*)d_in[1];
    const float* pm_w    = (const float*)d_in[2];
    const float* pm_b    = (const float*)d_in[3];
    const float* g_w     = (const float*)d_in[4];
    const float* g_b     = (const float*)d_in[5];
    const float* th_w    = (const float*)d_in[6];
    const float* th_b    = (const float*)d_in[7];
    const float* ph_w    = (const float*)d_in[8];
    const float* ph_b    = (const float*)d_in[9];
    const float* out_w   = (const float*)d_in[10];
    const float* gamma   = (const float*)d_in[11];
    const float* beta    = (const float*)d_in[12];
    const float* mean    = (const float*)d_in[13];
    const float* var     = (const float*)d_in[14];
    char* ws = (char*)d_ws;
    float* out = (float*)d_out;

    if (ws_size < WS_BYTES) return;

    prep_kernel<<<512, 256, 0, stream>>>(pm_w, g_w, th_w, ph_w, out_w, gamma, beta, mean, var, ws);
    lawin_main<<<NBATCH, 512, 0, stream>>>(query, context, pm_b, th_b, ph_b, g_b, ws, out);
}

// Round 7
// 787.474 us; speedup vs baseline: 1.4237x; 1.2387x over previous
//
#include <hip/hip_runtime.h>

#define NBATCH 2048

typedef __attribute__((ext_vector_type(8))) short short8;
typedef __attribute__((ext_vector_type(4))) short short4v;
typedef __attribute__((ext_vector_type(4))) float f32x4;
typedef __attribute__((ext_vector_type(4))) unsigned short us4;

__device__ __forceinline__ unsigned short f2bf(float f) {
    unsigned int u = __float_as_uint(f);
    u += 0x7FFFu + ((u >> 16) & 1u);
    return (unsigned short)(u >> 16);
}

__device__ __forceinline__ short4v pack4(f32x4 v) {
    short4v r;
    r[0] = (short)f2bf(v[0]); r[1] = (short)f2bf(v[1]);
    r[2] = (short)f2bf(v[2]); r[3] = (short)f2bf(v[3]);
    return r;
}
__device__ __forceinline__ short8 pack8(f32x4 lo, f32x4 hi) {
    short8 r;
    r[0] = (short)f2bf(lo[0]); r[1] = (short)f2bf(lo[1]);
    r[2] = (short)f2bf(lo[2]); r[3] = (short)f2bf(lo[3]);
    r[4] = (short)f2bf(hi[0]); r[5] = (short)f2bf(hi[1]);
    r[6] = (short)f2bf(hi[2]); r[7] = (short)f2bf(hi[3]);
    return r;
}

__device__ __forceinline__ f32x4 mfma16(short4v a, short4v b, f32x4 c) {
#if __has_builtin(__builtin_amdgcn_mfma_f32_16x16x16bf16_1k)
    return __builtin_amdgcn_mfma_f32_16x16x16bf16_1k(a, b, c, 0, 0, 0);
#elif __has_builtin(__builtin_amdgcn_mfma_f32_16x16x16_bf16)
    return __builtin_amdgcn_mfma_f32_16x16x16_bf16(a, b, c, 0, 0, 0);
#else
    asm volatile("v_mfma_f32_16x16x16_bf16 %0, %1, %2, %0" : "+v"(c) : "v"(a), "v"(b));
    return c;
#endif
}
#define MFMA32(a, b, c) __builtin_amdgcn_mfma_f32_16x16x32_bf16(a, b, c, 0, 0, 0)

#define SW(t) ((((t) ^ ((t) >> 3)) & 7) << 4)

// ws layout (bytes)
#define IW_OFF    0u        // I64 bf16 [64][64] (row out, k in)
#define PMW_OFF   8192u     // (pm_w + I) bf16 [4][64][64]
#define THW_OFF   40960u    // [256][512] bf16
#define PHW_OFF   303104u   // [256][512] bf16
#define GW_OFF    565248u   // [256][512] bf16
#define OUTW_OFF  827392u   // [512][256] bf16 (BN-scaled)
#define OUTB_OFF  1089536u  // [512] f32 (folded BN bias)
#define WS_BYTES  1091584u

__global__ void prep_kernel(const float* __restrict__ pm_w, const float* __restrict__ g_w,
                            const float* __restrict__ th_w, const float* __restrict__ ph_w,
                            const float* __restrict__ out_w, const float* __restrict__ gamma,
                            const float* __restrict__ beta, const float* __restrict__ mean,
                            const float* __restrict__ var, char* __restrict__ ws) {
    int i = blockIdx.x * 256 + threadIdx.x;
    unsigned short* iw  = (unsigned short*)(ws + IW_OFF);
    unsigned short* pmw = (unsigned short*)(ws + PMW_OFF);
    unsigned short* thw = (unsigned short*)(ws + THW_OFF);
    unsigned short* phw = (unsigned short*)(ws + PHW_OFF);
    unsigned short* gww = (unsigned short*)(ws + GW_OFF);
    unsigned short* oww = (unsigned short*)(ws + OUTW_OFF);
    float* ob = (float*)(ws + OUTB_OFF);
    if (i < 4096) iw[i] = f2bf(((i >> 6) == (i & 63)) ? 1.0f : 0.0f);
    if (i < 16384) {
        float ident = (((i >> 6) & 63) == (i & 63)) ? 1.0f : 0.0f;
        pmw[i] = f2bf(pm_w[i] + ident);
    }
    if (i < 131072) {
        thw[i] = f2bf(th_w[i]);
        phw[i] = f2bf(ph_w[i]);
        gww[i] = f2bf(g_w[i]);
        int o = i >> 8;
        float inv = gamma[o] * rsqrtf(var[o] + 1e-5f);
        oww[i] = f2bf(out_w[i] * inv);
    }
    if (i < 512) {
        float inv = gamma[i] * rsqrtf(var[i] + 1e-5f);
        ob[i] = beta[i] - mean[i] * inv;
    }
}

// Bulk MFMA-transpose stage: rows [wid*64, wid*64+64) of src (f32 [512][64])
// are token-mixed by Bm (I for q, pm_w+I for ctx) and stored into the 64KB
// frag-array dst as D[c][m] tiles (8B us4 stores, MFMA32-frag layout).
// All HBM loads are bulk float4 pairs -> high MLP, no dependent chains.
template<bool WITH_BIAS>
__device__ __forceinline__ void stage_T(const float* __restrict__ src,
                                        const char* __restrict__ Bm,
                                        const float* __restrict__ bias,
                                        char* __restrict__ dst,
                                        int wid, int l15, int l4) {
    const int cb0 = wid * 64;
    #pragma unroll 1
    for (int mth = 0; mth < 2; ++mth) {   // mth only feeds addresses; acc local per iter
        f32x4 acc[4][2] = {};
        #pragma unroll
        for (int ks = 0; ks < 2; ++ks) {
            short8 a[4], bb[2];
            #pragma unroll
            for (int ct = 0; ct < 4; ++ct) {
                const float* p = src + (cb0 + ct * 16 + l15) * 64 + ks * 32 + l4 * 8;
                a[ct] = pack8(*(const f32x4*)p, *(const f32x4*)(p + 4));
            }
            #pragma unroll
            for (int mt2 = 0; mt2 < 2; ++mt2)
                bb[mt2] = *(const short8*)(Bm + (mth * 32 + mt2 * 16 + l15) * 128 + ks * 64 + l4 * 16);
            #pragma unroll
            for (int ct = 0; ct < 4; ++ct)
                #pragma unroll
                for (int mt2 = 0; mt2 < 2; ++mt2)
                    acc[ct][mt2] = MFMA32(a[ct], bb[mt2], acc[ct][mt2]);
        }
        #pragma unroll
        for (int ct = 0; ct < 4; ++ct)
            #pragma unroll
            for (int mt2 = 0; mt2 < 2; ++mt2) {
                f32x4 v = acc[ct][mt2];
                if (WITH_BIAS) v += bias[mth * 32 + mt2 * 16 + l15];
                us4 pk;
                pk[0] = f2bf(v[0]); pk[1] = f2bf(v[1]); pk[2] = f2bf(v[2]); pk[3] = f2bf(v[3]);
                const int c32 = wid * 2 + (ct >> 1);
                const int mt = mth * 2 + mt2;
                const int lanep = ((ct & 1) * 2 + (l4 >> 1)) * 16 + l15;
                *(us4*)(dst + (c32 * 4 + mt) * 1024 + lanep * 16 + (l4 & 1) * 8) = pk;
            }
    }
}

// One batch per block, 8 waves (wave = (head h=wid>>1, nq-half)). 64KB LDS,
// 2 blocks/CU (128KB of the 160KB/CU). Single buffer FR, time-multiplexed:
//   T0: q^T frag-array (64KB)  ->  T1 consumes it into Theta regs
//   T2: ctx' frag-array (64KB) overwrites  ->  T3/T4 consume
//   Y^T bf16 [64][256] (32KB, SW-swizzled) overwrites -> T5 consumes
// All MFMA big operands come from LDS (ds_read_b128 lane*16, conflict-free)
// or L2 weights; HBM touched only by bulk staging + residual + out.
// rule #20: all reg-array-indexing loops fully unrolled.
__global__ __launch_bounds__(512, 4)
void lawin_main(const float* __restrict__ query, const float* __restrict__ context,
                const float* __restrict__ pm_b, const float* __restrict__ th_b,
                const float* __restrict__ ph_b, const float* __restrict__ g_b,
                const char* __restrict__ ws, float* __restrict__ out) {
    __shared__ __align__(16) char FR[65536];

    const char* iw  = ws + IW_OFF;
    const char* pmw = ws + PMW_OFF;
    const char* thw = ws + THW_OFF;
    const char* phw = ws + PHW_OFF;
    const char* gww = ws + GW_OFF;
    const char* oww = ws + OUTW_OFF;
    const float* ob = (const float*)(ws + OUTB_OFF);

    const int b = blockIdx.x;
    const int tid = threadIdx.x;
    const int wid = tid >> 6;
    const int lane = tid & 63;
    const int l15 = lane & 15;
    const int l4 = lane >> 4;
    const int h = wid >> 1;
    const int half = wid & 1;
    const int nqbase = half * 32;
    const int nqt = half * 2;          // nq 16-tile base

    const float* qb = query + (size_t)b * 32768;
    const float* cbp = context + (size_t)b * 32768;
    float* outb = out + (size_t)b * 32768;

    // ---------- T0: q -> q^T frag-array in FR (bulk, B = I) ----------
    stage_T<false>(qb, iw, nullptr, FR, wid, l15, l4);
    __syncthreads();

    // ---------- T1: Theta[d][nq] = thw x q^T; A from L2, B from LDS ----------
    short4v thB[4][2];   // [d16-tile][nq16-tile] as S-mfma B-frags
    {
        f32x4 acc[4][2] = {};
        #pragma unroll 2
        for (int ks = 0; ks < 16; ++ks) {
            short8 a[4], bb[2];
            #pragma unroll
            for (int td = 0; td < 4; ++td)
                a[td] = *(const short8*)(thw + (h * 64 + td * 16 + l15) * 1024 + ks * 64 + l4 * 16);
            #pragma unroll
            for (int tb = 0; tb < 2; ++tb)
                bb[tb] = *(const short8*)(FR + (ks * 4 + nqt + tb) * 1024 + lane * 16);
            #pragma unroll
            for (int td = 0; td < 4; ++td)
                #pragma unroll
                for (int tb = 0; tb < 2; ++tb)
                    acc[td][tb] = MFMA32(a[td], bb[tb], acc[td][tb]);
        }
        #pragma unroll
        for (int td = 0; td < 4; ++td) {
            f32x4 bv = *(const f32x4*)(th_b + h * 64 + td * 16 + l4 * 4);
            #pragma unroll
            for (int tb = 0; tb < 2; ++tb)
                thB[td][tb] = pack4(acc[td][tb] + bv);
        }
    }
    __syncthreads();   // all waves done reading q^T

    // ---------- T2: posmix (residual folded into W+I) -> ctx' frag-array ----------
    stage_T<true>(cbp, pmw + h * 8192, pm_b + h * 64, FR, wid, l15, l4);
    __syncthreads();

    // ---------- T3: Phi -> S^T -> softmax -> pB ----------
    short4v pB[4][2];    // [nc16-tile][nq16-tile] PV A-frags
    {
        f32x4 s_acc[4][2] = {};   // S^T tiles: row=nc(l4*4+r), col=nq(l15)
        #pragma unroll
        for (int dh = 0; dh < 2; ++dh) {          // FULL unroll: indexes thB
            #pragma unroll
            for (int tch = 0; tch < 2; ++tch) {   // FULL unroll: indexes s_acc
                f32x4 pacc[2][2] = {};   // Phi D[d][nc]: [td2][tc2]
                #pragma unroll 2
                for (int ks = 0; ks < 16; ++ks) {
                    short8 a[2], bb[2];
                    #pragma unroll
                    for (int td2 = 0; td2 < 2; ++td2)
                        a[td2] = *(const short8*)(phw + (h * 64 + dh * 32 + td2 * 16 + l15) * 1024 + ks * 64 + l4 * 16);
                    #pragma unroll
                    for (int tc2 = 0; tc2 < 2; ++tc2)
                        bb[tc2] = *(const short8*)(FR + (ks * 4 + tch * 2 + tc2) * 1024 + lane * 16);
                    #pragma unroll
                    for (int td2 = 0; td2 < 2; ++td2)
                        #pragma unroll
                        for (int tc2 = 0; tc2 < 2; ++tc2)
                            pacc[td2][tc2] = MFMA32(a[td2], bb[tc2], pacc[td2][tc2]);
                }
                #pragma unroll
                for (int td2 = 0; td2 < 2; ++td2) {
                    f32x4 bv = *(const f32x4*)(ph_b + h * 64 + dh * 32 + td2 * 16 + l4 * 4);
                    #pragma unroll
                    for (int tc2 = 0; tc2 < 2; ++tc2) {
                        short4v phB = pack4(pacc[td2][tc2] + bv);
                        #pragma unroll
                        for (int tb = 0; tb < 2; ++tb)
                            s_acc[tch * 2 + tc2][tb] = mfma16(phB, thB[dh * 2 + td2][tb], s_acc[tch * 2 + tc2][tb]);
                    }
                }
            }
        }
        // softmax over nc (per-lane 16 values + shfl over l4), scale 1/8
        #pragma unroll
        for (int tb = 0; tb < 2; ++tb) {
            float mx = -1e30f;
            #pragma unroll
            for (int tc = 0; tc < 4; ++tc)
                #pragma unroll
                for (int r = 0; r < 4; ++r) mx = fmaxf(mx, s_acc[tc][tb][r]);
            mx = fmaxf(mx, __shfl_xor(mx, 16));
            mx = fmaxf(mx, __shfl_xor(mx, 32));
            float sum = 0.f;
            #pragma unroll
            for (int tc = 0; tc < 4; ++tc)
                #pragma unroll
                for (int r = 0; r < 4; ++r) {
                    float v = __expf((s_acc[tc][tb][r] - mx) * 0.125f);
                    s_acc[tc][tb][r] = v;
                    sum += v;
                }
            sum += __shfl_xor(sum, 16);
            sum += __shfl_xor(sum, 32);
            float rinv = 1.0f / sum;
            #pragma unroll
            for (int tc = 0; tc < 4; ++tc)
                pB[tc][tb] = pack4(s_acc[tc][tb] * rinv);
        }
    }

    // ---------- T4: G^T and PV chain -> y_acc ----------
    f32x4 y_acc[2][4] = {};    // [nq-tile][dg16-tile], row=nq, col=dg
    #pragma unroll
    for (int gh = 0; gh < 2; ++gh) {              // FULL unroll: indexes y_acc
        #pragma unroll
        for (int tnch = 0; tnch < 2; ++tnch) {    // FULL unroll: indexes pB
            f32x4 gacc[2][2] = {};   // G D[nc][dg]: [tn][tg]
            #pragma unroll 2
            for (int ks = 0; ks < 16; ++ks) {
                short8 a[2], bb[2];
                #pragma unroll
                for (int tn = 0; tn < 2; ++tn)
                    a[tn] = *(const short8*)(FR + (ks * 4 + tnch * 2 + tn) * 1024 + lane * 16);
                #pragma unroll
                for (int tg = 0; tg < 2; ++tg)
                    bb[tg] = *(const short8*)(gww + (h * 64 + gh * 32 + tg * 16 + l15) * 1024 + ks * 64 + l4 * 16);
                #pragma unroll
                for (int tn = 0; tn < 2; ++tn)
                    #pragma unroll
                    for (int tg = 0; tg < 2; ++tg)
                        gacc[tn][tg] = MFMA32(a[tn], bb[tg], gacc[tn][tg]);
            }
            #pragma unroll
            for (int tg = 0; tg < 2; ++tg) {
                float gbv = g_b[h * 64 + gh * 32 + tg * 16 + l15];
                #pragma unroll
                for (int tn = 0; tn < 2; ++tn) {
                    short4v gB = pack4(gacc[tn][tg] + gbv);
                    #pragma unroll
                    for (int tb = 0; tb < 2; ++tb)
                        y_acc[tb][gh * 2 + tg] = mfma16(pB[tnch * 2 + tn][tb], gB, y_acc[tb][gh * 2 + tg]);
                }
            }
        }
    }
    __syncthreads();   // all waves done reading ctx' frags

    // ---------- Y^T bf16 [64][256] (SW-swizzled) -> FR[0:32K) ----------
    #pragma unroll
    for (int tb = 0; tb < 2; ++tb)
        #pragma unroll
        for (int tdg = 0; tdg < 4; ++tdg)
            #pragma unroll
            for (int r = 0; r < 4; ++r) {
                int nq = nqbase + tb * 16 + l4 * 4 + r;
                int dg = h * 64 + tdg * 16 + l15;
                *(unsigned short*)(FR + nq * 512 + ((2 * dg) ^ SW(nq))) = f2bf(y_acc[tb][tdg][r]);
            }
    __syncthreads();

    // ---------- T5: out-proj (BN folded) + bias + f32 query residual ----------
    #pragma unroll 1
    for (int och = 0; och < 2; ++och) {    // och only feeds addresses; acc local per iter
        const int ob0 = wid * 64 + och * 32;
        f32x4 acc[4][2] = {};
        #pragma unroll 2
        for (int ks = 0; ks < 8; ++ks) {
            const int kb = ks * 64 + l4 * 16;
            short8 a[4], bb[2];
            #pragma unroll
            for (int tr = 0; tr < 4; ++tr) {
                int tok = tr * 16 + l15;
                a[tr] = *(const short8*)(FR + tok * 512 + (kb ^ SW(tok)));
            }
            #pragma unroll
            for (int oc = 0; oc < 2; ++oc)
                bb[oc] = *(const short8*)(oww + (ob0 + oc * 16 + l15) * 512 + kb);
            #pragma unroll
            for (int tr = 0; tr < 4; ++tr)
                #pragma unroll
                for (int oc = 0; oc < 2; ++oc)
                    acc[tr][oc] = MFMA32(a[tr], bb[oc], acc[tr][oc]);
        }
        #pragma unroll
        for (int oc = 0; oc < 2; ++oc) {
            const int o = ob0 + oc * 16 + l15;
            const float bias = ob[o];
            #pragma unroll
            for (int tr = 0; tr < 4; ++tr) {
                const int tt = tr * 16 + l4 * 4;
                f32x4 qv = *(const f32x4*)(qb + o * 64 + tt);
                f32x4 ov;
                #pragma unroll
                for (int r = 0; r < 4; ++r) ov[r] = acc[tr][oc][r] + bias + qv[r];
                *(f32x4*)(outb + o * 64 + tt) = ov;
            }
        }
    }
}

extern "C" void kernel_launch(void* const* d_in, const int* in_sizes, int n_in,
                              void* d_out, int out_size, void* d_ws, size_t ws_size,
                              hipStream_t stream) {
    const float* query   = (const float*)d_in[0];
    const float* context = (const float*)d_in[1];
    const float* pm_w    = (const float*)d_in[2];
    const float* pm_b    = (const float*)d_in[3];
    const float* g_w     = (const float*)d_in[4];
    const float* g_b     = (const float*)d_in[5];
    const float* th_w    = (const float*)d_in[6];
    const float* th_b    = (const float*)d_in[7];
    const float* ph_w    = (const float*)d_in[8];
    const float* ph_b    = (const float*)d_in[9];
    const float* out_w   = (const float*)d_in[10];
    const float* gamma   = (const float*)d_in[11];
    const float* beta    = (const float*)d_in[12];
    const float* mean    = (const float*)d_in[13];
    const float* var     = (const float*)d_in[14];
    char* ws = (char*)d_ws;
    float* out = (float*)d_out;

    if (ws_size < WS_BYTES) return;

    prep_kernel<<<512, 256, 0, stream>>>(pm_w, g_w, th_w, ph_w, out_w, gamma, beta, mean, var, ws);
    lawin_main<<<NBATCH, 512, 0, stream>>>(query, context, pm_b, th_b, ph_b, g_b, ws, out);
}

// Round 8
// 605.442 us; speedup vs baseline: 1.8517x; 1.3007x over previous
//
#include <hip/hip_runtime.h>

#define NBATCH 2048

typedef __attribute__((ext_vector_type(8))) short short8;
typedef __attribute__((ext_vector_type(4))) short short4v;
typedef __attribute__((ext_vector_type(4))) float f32x4;
typedef __attribute__((ext_vector_type(4))) unsigned short us4;

__device__ __forceinline__ unsigned short f2bf(float f) {
    unsigned int u = __float_as_uint(f);
    u += 0x7FFFu + ((u >> 16) & 1u);
    return (unsigned short)(u >> 16);
}

__device__ __forceinline__ short4v pack4(f32x4 v) {
    short4v r;
    r[0] = (short)f2bf(v[0]); r[1] = (short)f2bf(v[1]);
    r[2] = (short)f2bf(v[2]); r[3] = (short)f2bf(v[3]);
    return r;
}
__device__ __forceinline__ short8 pack8(f32x4 lo, f32x4 hi) {
    short8 r;
    r[0] = (short)f2bf(lo[0]); r[1] = (short)f2bf(lo[1]);
    r[2] = (short)f2bf(lo[2]); r[3] = (short)f2bf(lo[3]);
    r[4] = (short)f2bf(hi[0]); r[5] = (short)f2bf(hi[1]);
    r[6] = (short)f2bf(hi[2]); r[7] = (short)f2bf(hi[3]);
    return r;
}

__device__ __forceinline__ f32x4 mfma16(short4v a, short4v b, f32x4 c) {
#if __has_builtin(__builtin_amdgcn_mfma_f32_16x16x16bf16_1k)
    return __builtin_amdgcn_mfma_f32_16x16x16bf16_1k(a, b, c, 0, 0, 0);
#elif __has_builtin(__builtin_amdgcn_mfma_f32_16x16x16_bf16)
    return __builtin_amdgcn_mfma_f32_16x16x16_bf16(a, b, c, 0, 0, 0);
#else
    asm volatile("v_mfma_f32_16x16x16_bf16 %0, %1, %2, %0" : "+v"(c) : "v"(a), "v"(b));
    return c;
#endif
}
#define MFMA32(a, b, c) __builtin_amdgcn_mfma_f32_16x16x32_bf16(a, b, c, 0, 0, 0)

#define SW(t) ((((t) ^ ((t) >> 3)) & 7) << 4)

// ws layout (bytes)
#define IW_OFF    0u        // I64 bf16 [64][64] (row out, k in)
#define PMW_OFF   8192u     // (pm_w + I) bf16 [4][64][64]
#define THW_OFF   40960u    // [256][512] bf16
#define PHW_OFF   303104u   // [256][512] bf16
#define GW_OFF    565248u   // [256][512] bf16
#define OUTW_OFF  827392u   // [512][256] bf16 (BN-scaled)
#define OUTB_OFF  1089536u  // [512] f32 (folded BN bias)
#define WS_BYTES  1091584u

__global__ void prep_kernel(const float* __restrict__ pm_w, const float* __restrict__ g_w,
                            const float* __restrict__ th_w, const float* __restrict__ ph_w,
                            const float* __restrict__ out_w, const float* __restrict__ gamma,
                            const float* __restrict__ beta, const float* __restrict__ mean,
                            const float* __restrict__ var, char* __restrict__ ws) {
    int i = blockIdx.x * 256 + threadIdx.x;
    unsigned short* iw  = (unsigned short*)(ws + IW_OFF);
    unsigned short* pmw = (unsigned short*)(ws + PMW_OFF);
    unsigned short* thw = (unsigned short*)(ws + THW_OFF);
    unsigned short* phw = (unsigned short*)(ws + PHW_OFF);
    unsigned short* gww = (unsigned short*)(ws + GW_OFF);
    unsigned short* oww = (unsigned short*)(ws + OUTW_OFF);
    float* ob = (float*)(ws + OUTB_OFF);
    if (i < 4096) iw[i] = f2bf(((i >> 6) == (i & 63)) ? 1.0f : 0.0f);
    if (i < 16384) {
        float ident = (((i >> 6) & 63) == (i & 63)) ? 1.0f : 0.0f;
        pmw[i] = f2bf(pm_w[i] + ident);
    }
    if (i < 131072) {
        thw[i] = f2bf(th_w[i]);
        phw[i] = f2bf(ph_w[i]);
        gww[i] = f2bf(g_w[i]);
        int o = i >> 8;
        float inv = gamma[o] * rsqrtf(var[o] + 1e-5f);
        oww[i] = f2bf(out_w[i] * inv);
    }
    if (i < 512) {
        float inv = gamma[i] * rsqrtf(var[i] + 1e-5f);
        ob[i] = beta[i] - mean[i] * inv;
    }
}

// Bulk MFMA-transpose stage (unchanged math from R7): rows [wid*64,+64) of
// src (f32 [512][64]) token-mixed by Bm, stored into the 64KB frag-array.
template<bool WITH_BIAS>
__device__ __forceinline__ void stage_T(const float* __restrict__ src,
                                        const char* __restrict__ Bm,
                                        const float* __restrict__ bias,
                                        char* __restrict__ dst,
                                        int wid, int l15, int l4) {
    const int cb0 = wid * 64;
    #pragma unroll
    for (int mth = 0; mth < 2; ++mth) {
        f32x4 acc[4][2] = {};
        #pragma unroll
        for (int ks = 0; ks < 2; ++ks) {
            short8 a[4], bb[2];
            #pragma unroll
            for (int ct = 0; ct < 4; ++ct) {
                const float* p = src + (cb0 + ct * 16 + l15) * 64 + ks * 32 + l4 * 8;
                a[ct] = pack8(*(const f32x4*)p, *(const f32x4*)(p + 4));
            }
            #pragma unroll
            for (int mt2 = 0; mt2 < 2; ++mt2)
                bb[mt2] = *(const short8*)(Bm + (mth * 32 + mt2 * 16 + l15) * 128 + ks * 64 + l4 * 16);
            #pragma unroll
            for (int ct = 0; ct < 4; ++ct)
                #pragma unroll
                for (int mt2 = 0; mt2 < 2; ++mt2)
                    acc[ct][mt2] = MFMA32(a[ct], bb[mt2], acc[ct][mt2]);
        }
        #pragma unroll
        for (int ct = 0; ct < 4; ++ct)
            #pragma unroll
            for (int mt2 = 0; mt2 < 2; ++mt2) {
                f32x4 v = acc[ct][mt2];
                if (WITH_BIAS) v += bias[mth * 32 + mt2 * 16 + l15];
                us4 pk;
                pk[0] = f2bf(v[0]); pk[1] = f2bf(v[1]); pk[2] = f2bf(v[2]); pk[3] = f2bf(v[3]);
                const int c32 = wid * 2 + (ct >> 1);
                const int mt = mth * 2 + mt2;
                const int lanep = ((ct & 1) * 2 + (l4 >> 1)) * 16 + l15;
                *(us4*)(dst + (c32 * 4 + mt) * 1024 + lanep * 16 + (l4 & 1) * 8) = pk;
            }
    }
}

// One batch per block, 8 waves (wave=(head h, nq-half)). 64KB LDS, 1 block/CU.
// launch_bounds(512,2): 256-reg cap. DELIBERATE: the (512,4) 128-cap left
// ~64 arch VGPRs after AGPRs, forcing the allocator to serialize VMEM loads
// (MLP~1, ~300k stall-cycles/block — R4..R7 all latency-bound at 12% pipes).
// Fat transients + unroll-4 ks loops buy ~24 loads in flight per wave.
// T3/T4 merged so each weight row is loaded ONCE (was twice).
// rule #20: all reg-array subscripts compile-time (full unroll).
__global__ __launch_bounds__(512, 2)
void lawin_main(const float* __restrict__ query, const float* __restrict__ context,
                const float* __restrict__ pm_b, const float* __restrict__ th_b,
                const float* __restrict__ ph_b, const float* __restrict__ g_b,
                const char* __restrict__ ws, float* __restrict__ out) {
    __shared__ __align__(16) char FR[65536];

    const char* iw  = ws + IW_OFF;
    const char* pmw = ws + PMW_OFF;
    const char* thw = ws + THW_OFF;
    const char* phw = ws + PHW_OFF;
    const char* gww = ws + GW_OFF;
    const char* oww = ws + OUTW_OFF;
    const float* ob = (const float*)(ws + OUTB_OFF);

    const int b = blockIdx.x;
    const int tid = threadIdx.x;
    const int wid = tid >> 6;
    const int lane = tid & 63;
    const int l15 = lane & 15;
    const int l4 = lane >> 4;
    const int h = wid >> 1;
    const int half = wid & 1;
    const int nqbase = half * 32;
    const int nqt = half * 2;          // nq 16-tile base

    const float* qb = query + (size_t)b * 32768;
    const float* cbp = context + (size_t)b * 32768;
    float* outb = out + (size_t)b * 32768;

    // ---------- T0: q -> q^T frag-array in FR (bulk, B = I) ----------
    stage_T<false>(qb, iw, nullptr, FR, wid, l15, l4);
    __syncthreads();

    // ---------- T1: Theta[d][nq] = thw x q^T; A from L2, B from LDS ----------
    short4v thB[4][2];   // [d16-tile][nq16-tile] as S-mfma B-frags
    {
        f32x4 acc[4][2] = {};
        #pragma unroll 4
        for (int ks = 0; ks < 16; ++ks) {
            short8 a[4], bb[2];
            #pragma unroll
            for (int td = 0; td < 4; ++td)
                a[td] = *(const short8*)(thw + (h * 64 + td * 16 + l15) * 1024 + ks * 64 + l4 * 16);
            #pragma unroll
            for (int tb = 0; tb < 2; ++tb)
                bb[tb] = *(const short8*)(FR + (ks * 4 + nqt + tb) * 1024 + lane * 16);
            #pragma unroll
            for (int td = 0; td < 4; ++td)
                #pragma unroll
                for (int tb = 0; tb < 2; ++tb)
                    acc[td][tb] = MFMA32(a[td], bb[tb], acc[td][tb]);
        }
        #pragma unroll
        for (int td = 0; td < 4; ++td) {
            f32x4 bv = *(const f32x4*)(th_b + h * 64 + td * 16 + l4 * 4);
            #pragma unroll
            for (int tb = 0; tb < 2; ++tb)
                thB[td][tb] = pack4(acc[td][tb] + bv);
        }
    }
    __syncthreads();   // all waves done reading q^T

    // ---------- T2: posmix (residual folded into W+I) -> ctx' frag-array ----------
    stage_T<true>(cbp, pmw + h * 8192, pm_b + h * 64, FR, wid, l15, l4);
    __syncthreads();

    // ---------- T3: Phi -> S^T -> softmax -> pB (weights loaded ONCE per row) ----------
    short4v pB[4][2];    // [nc16-tile][nq16-tile] PV A-frags
    {
        f32x4 s_acc[4][2] = {};   // S^T tiles: row=nc(l4*4+r), col=nq(l15)
        #pragma unroll
        for (int dh = 0; dh < 2; ++dh) {          // FULL unroll: indexes thB
            f32x4 pacc[2][2][2] = {};   // Phi D[d][nc]: [tch][td2][tc2]
            #pragma unroll 4
            for (int ks = 0; ks < 16; ++ks) {
                short8 a[2], bb[4];
                #pragma unroll
                for (int td2 = 0; td2 < 2; ++td2)
                    a[td2] = *(const short8*)(phw + (h * 64 + dh * 32 + td2 * 16 + l15) * 1024 + ks * 64 + l4 * 16);
                #pragma unroll
                for (int tc = 0; tc < 4; ++tc)
                    bb[tc] = *(const short8*)(FR + (ks * 4 + tc) * 1024 + lane * 16);
                #pragma unroll
                for (int tch = 0; tch < 2; ++tch)
                    #pragma unroll
                    for (int td2 = 0; td2 < 2; ++td2)
                        #pragma unroll
                        for (int tc2 = 0; tc2 < 2; ++tc2)
                            pacc[tch][td2][tc2] = MFMA32(a[td2], bb[tch * 2 + tc2], pacc[tch][td2][tc2]);
            }
            #pragma unroll
            for (int tch = 0; tch < 2; ++tch)
                #pragma unroll
                for (int td2 = 0; td2 < 2; ++td2) {
                    f32x4 bv = *(const f32x4*)(ph_b + h * 64 + dh * 32 + td2 * 16 + l4 * 4);
                    #pragma unroll
                    for (int tc2 = 0; tc2 < 2; ++tc2) {
                        short4v phB = pack4(pacc[tch][td2][tc2] + bv);
                        #pragma unroll
                        for (int tb = 0; tb < 2; ++tb)
                            s_acc[tch * 2 + tc2][tb] = mfma16(phB, thB[dh * 2 + td2][tb], s_acc[tch * 2 + tc2][tb]);
                    }
                }
        }
        // softmax over nc (per-lane 16 values + shfl over l4), scale 1/8
        #pragma unroll
        for (int tb = 0; tb < 2; ++tb) {
            float mx = -1e30f;
            #pragma unroll
            for (int tc = 0; tc < 4; ++tc)
                #pragma unroll
                for (int r = 0; r < 4; ++r) mx = fmaxf(mx, s_acc[tc][tb][r]);
            mx = fmaxf(mx, __shfl_xor(mx, 16));
            mx = fmaxf(mx, __shfl_xor(mx, 32));
            float sum = 0.f;
            #pragma unroll
            for (int tc = 0; tc < 4; ++tc)
                #pragma unroll
                for (int r = 0; r < 4; ++r) {
                    float v = __expf((s_acc[tc][tb][r] - mx) * 0.125f);
                    s_acc[tc][tb][r] = v;
                    sum += v;
                }
            sum += __shfl_xor(sum, 16);
            sum += __shfl_xor(sum, 32);
            float rinv = 1.0f / sum;
            #pragma unroll
            for (int tc = 0; tc < 4; ++tc)
                pB[tc][tb] = pack4(s_acc[tc][tb] * rinv);
        }
    }

    // ---------- T4: G^T and PV chain -> y_acc (weights loaded ONCE per row) ----------
    f32x4 y_acc[2][4] = {};    // [nq-tile][dg16-tile], row=nq, col=dg
    #pragma unroll
    for (int gh = 0; gh < 2; ++gh) {              // FULL unroll: indexes y_acc
        f32x4 gacc[2][2][2] = {};   // G D[nc][dg]: [tnch][tn][tg]
        #pragma unroll 4
        for (int ks = 0; ks < 16; ++ks) {
            short8 a[4], bb[2];
            #pragma unroll
            for (int tn = 0; tn < 4; ++tn)
                a[tn] = *(const short8*)(FR + (ks * 4 + tn) * 1024 + lane * 16);
            #pragma unroll
            for (int tg = 0; tg < 2; ++tg)
                bb[tg] = *(const short8*)(gww + (h * 64 + gh * 32 + tg * 16 + l15) * 1024 + ks * 64 + l4 * 16);
            #pragma unroll
            for (int tnch = 0; tnch < 2; ++tnch)
                #pragma unroll
                for (int tn = 0; tn < 2; ++tn)
                    #pragma unroll
                    for (int tg = 0; tg < 2; ++tg)
                        gacc[tnch][tn][tg] = MFMA32(a[tnch * 2 + tn], bb[tg], gacc[tnch][tn][tg]);
        }
        #pragma unroll
        for (int tnch = 0; tnch < 2; ++tnch)
            #pragma unroll
            for (int tg = 0; tg < 2; ++tg) {
                float gbv = g_b[h * 64 + gh * 32 + tg * 16 + l15];
                #pragma unroll
                for (int tn = 0; tn < 2; ++tn) {
                    short4v gB = pack4(gacc[tnch][tn][tg] + gbv);
                    #pragma unroll
                    for (int tb = 0; tb < 2; ++tb)
                        y_acc[tb][gh * 2 + tg] = mfma16(pB[tnch * 2 + tn][tb], gB, y_acc[tb][gh * 2 + tg]);
                }
            }
    }
    __syncthreads();   // all waves done reading ctx' frags

    // ---------- Y^T bf16 [64][256] (SW-swizzled) -> FR[0:32K) ----------
    #pragma unroll
    for (int tb = 0; tb < 2; ++tb)
        #pragma unroll
        for (int tdg = 0; tdg < 4; ++tdg)
            #pragma unroll
            for (int r = 0; r < 4; ++r) {
                int nq = nqbase + tb * 16 + l4 * 4 + r;
                int dg = h * 64 + tdg * 16 + l15;
                *(unsigned short*)(FR + nq * 512 + ((2 * dg) ^ SW(nq))) = f2bf(y_acc[tb][tdg][r]);
            }
    __syncthreads();

    // ---------- T5: out-proj (BN folded) + bias + f32 query residual ----------
    #pragma unroll 1
    for (int och = 0; och < 2; ++och) {    // och only feeds addresses; acc local per iter
        const int ob0 = wid * 64 + och * 32;
        f32x4 acc[4][2] = {};
        #pragma unroll 4
        for (int ks = 0; ks < 8; ++ks) {
            const int kb = ks * 64 + l4 * 16;
            short8 a[4], bb[2];
            #pragma unroll
            for (int tr = 0; tr < 4; ++tr) {
                int tok = tr * 16 + l15;
                a[tr] = *(const short8*)(FR + tok * 512 + (kb ^ SW(tok)));
            }
            #pragma unroll
            for (int oc = 0; oc < 2; ++oc)
                bb[oc] = *(const short8*)(oww + (ob0 + oc * 16 + l15) * 512 + kb);
            #pragma unroll
            for (int tr = 0; tr < 4; ++tr)
                #pragma unroll
                for (int oc = 0; oc < 2; ++oc)
                    acc[tr][oc] = MFMA32(a[tr], bb[oc], acc[tr][oc]);
        }
        #pragma unroll
        for (int oc = 0; oc < 2; ++oc) {
            const int o = ob0 + oc * 16 + l15;
            const float bias = ob[o];
            #pragma unroll
            for (int tr = 0; tr < 4; ++tr) {
                const int tt = tr * 16 + l4 * 4;
                f32x4 qv = *(const f32x4*)(qb + o * 64 + tt);
                f32x4 ov;
                #pragma unroll
                for (int r = 0; r < 4; ++r) ov[r] = acc[tr][oc][r] + bias + qv[r];
                *(f32x4*)(outb + o * 64 + tt) = ov;
            }
        }
    }
}

extern "C" void kernel_launch(void* const* d_in, const int* in_sizes, int n_in,
                              void* d_out, int out_size, void* d_ws, size_t ws_size,
                              hipStream_t stream) {
    const float* query   = (const float*)d_in[0];
    const float* context = (const float*)d_in[1];
    const float* pm_w    = (const float*)d_in[2];
    const float* pm_b    = (const float*)d_in[3];
    const float* g_w     = (const float*)d_in[4];
    const float* g_b     = (const float*)d_in[5];
    const float* th_w    = (const float*)d_in[6];
    const float* th_b    = (const float*)d_in[7];
    const float* ph_w    = (const float*)d_in[8];
    const float* ph_b    = (const float*)d_in[9];
    const float* out_w   = (const float*)d_in[10];
    const float* gamma   = (const float*)d_in[11];
    const float* beta    = (const float*)d_in[12];
    const float* mean    = (const float*)d_in[13];
    const float* var     = (const float*)d_in[14];
    char* ws = (char*)d_ws;
    float* out = (float*)d_out;

    if (ws_size < WS_BYTES) return;

    prep_kernel<<<512, 256, 0, stream>>>(pm_w, g_w, th_w, ph_w, out_w, gamma, beta, mean, var, ws);
    lawin_main<<<NBATCH, 512, 0, stream>>>(query, context, pm_b, th_b, ph_b, g_b, ws, out);
}

// Round 9
// 389.520 us; speedup vs baseline: 2.8781x; 1.5543x over previous
//
#include <hip/hip_runtime.h>

#define NBATCH 2048

typedef __attribute__((ext_vector_type(8))) short short8;
typedef __attribute__((ext_vector_type(4))) short short4v;
typedef __attribute__((ext_vector_type(4))) float f32x4;
typedef __attribute__((ext_vector_type(4))) unsigned short us4;

__device__ __forceinline__ unsigned short f2bf(float f) {
    unsigned int u = __float_as_uint(f);
    u += 0x7FFFu + ((u >> 16) & 1u);
    return (unsigned short)(u >> 16);
}

__device__ __forceinline__ short4v pack4(f32x4 v) {
    short4v r;
    r[0] = (short)f2bf(v[0]); r[1] = (short)f2bf(v[1]);
    r[2] = (short)f2bf(v[2]); r[3] = (short)f2bf(v[3]);
    return r;
}
__device__ __forceinline__ short8 pack8(f32x4 lo, f32x4 hi) {
    short8 r;
    r[0] = (short)f2bf(lo[0]); r[1] = (short)f2bf(lo[1]);
    r[2] = (short)f2bf(lo[2]); r[3] = (short)f2bf(lo[3]);
    r[4] = (short)f2bf(hi[0]); r[5] = (short)f2bf(hi[1]);
    r[6] = (short)f2bf(hi[2]); r[7] = (short)f2bf(hi[3]);
    return r;
}

__device__ __forceinline__ f32x4 mfma16(short4v a, short4v b, f32x4 c) {
#if __has_builtin(__builtin_amdgcn_mfma_f32_16x16x16bf16_1k)
    return __builtin_amdgcn_mfma_f32_16x16x16bf16_1k(a, b, c, 0, 0, 0);
#elif __has_builtin(__builtin_amdgcn_mfma_f32_16x16x16_bf16)
    return __builtin_amdgcn_mfma_f32_16x16x16_bf16(a, b, c, 0, 0, 0);
#else
    asm volatile("v_mfma_f32_16x16x16_bf16 %0, %1, %2, %0" : "+v"(c) : "v"(a), "v"(b));
    return c;
#endif
}
#define MFMA32(a, b, c) __builtin_amdgcn_mfma_f32_16x16x32_bf16(a, b, c, 0, 0, 0)

#define SW(t) ((((t) ^ ((t) >> 3)) & 7) << 4)

// ws layout (bytes)
#define IW_OFF    0u        // I64 bf16 [64][64]
#define PMW_OFF   8192u     // (pm_w + I) bf16 [4][64][64]
#define THW_OFF   40960u    // [256][512] bf16
#define PHW_OFF   303104u   // [256][512] bf16
#define GW_OFF    565248u   // [256][512] bf16
#define OUTW_OFF  827392u   // [512][256] bf16 (BN-scaled)
#define OUTB_OFF  1089536u  // [512] f32 (folded BN bias)
#define WS_BYTES  1091584u

__global__ void prep_kernel(const float* __restrict__ pm_w, const float* __restrict__ g_w,
                            const float* __restrict__ th_w, const float* __restrict__ ph_w,
                            const float* __restrict__ out_w, const float* __restrict__ gamma,
                            const float* __restrict__ beta, const float* __restrict__ mean,
                            const float* __restrict__ var, char* __restrict__ ws) {
    int i = blockIdx.x * 256 + threadIdx.x;
    unsigned short* iw  = (unsigned short*)(ws + IW_OFF);
    unsigned short* pmw = (unsigned short*)(ws + PMW_OFF);
    unsigned short* thw = (unsigned short*)(ws + THW_OFF);
    unsigned short* phw = (unsigned short*)(ws + PHW_OFF);
    unsigned short* gww = (unsigned short*)(ws + GW_OFF);
    unsigned short* oww = (unsigned short*)(ws + OUTW_OFF);
    float* ob = (float*)(ws + OUTB_OFF);
    if (i < 4096) iw[i] = f2bf(((i >> 6) == (i & 63)) ? 1.0f : 0.0f);
    if (i < 16384) {
        float ident = (((i >> 6) & 63) == (i & 63)) ? 1.0f : 0.0f;
        pmw[i] = f2bf(pm_w[i] + ident);
    }
    if (i < 131072) {
        thw[i] = f2bf(th_w[i]);
        phw[i] = f2bf(ph_w[i]);
        gww[i] = f2bf(g_w[i]);
        int o = i >> 8;
        float inv = gamma[o] * rsqrtf(var[o] + 1e-5f);
        oww[i] = f2bf(out_w[i] * inv);
    }
    if (i < 512) {
        float inv = gamma[i] * rsqrtf(var[i] + 1e-5f);
        ob[i] = beta[i] - mean[i] * inv;
    }
}

// Bulk MFMA-transpose stage (verified R7/R8): rows [cw*64, cw*64+64) of src
// (f32 [512][64]) token-mixed by Bm, stored into the 64KB frag-array dst.
template<bool WITH_BIAS>
__device__ __forceinline__ void stage_T(const float* __restrict__ src,
                                        const char* __restrict__ Bm,
                                        const float* __restrict__ bias,
                                        char* __restrict__ dst,
                                        int cw, int l15, int l4) {
    const int cb0 = cw * 64;
    #pragma unroll
    for (int mth = 0; mth < 2; ++mth) {
        f32x4 acc[4][2] = {};
        #pragma unroll
        for (int ks = 0; ks < 2; ++ks) {
            short8 a[4], bb[2];
            #pragma unroll
            for (int ct = 0; ct < 4; ++ct) {
                const float* p = src + (cb0 + ct * 16 + l15) * 64 + ks * 32 + l4 * 8;
                a[ct] = pack8(*(const f32x4*)p, *(const f32x4*)(p + 4));
            }
            #pragma unroll
            for (int mt2 = 0; mt2 < 2; ++mt2)
                bb[mt2] = *(const short8*)(Bm + (mth * 32 + mt2 * 16 + l15) * 128 + ks * 64 + l4 * 16);
            #pragma unroll
            for (int ct = 0; ct < 4; ++ct)
                #pragma unroll
                for (int mt2 = 0; mt2 < 2; ++mt2)
                    acc[ct][mt2] = MFMA32(a[ct], bb[mt2], acc[ct][mt2]);
        }
        #pragma unroll
        for (int ct = 0; ct < 4; ++ct)
            #pragma unroll
            for (int mt2 = 0; mt2 < 2; ++mt2) {
                f32x4 v = acc[ct][mt2];
                if (WITH_BIAS) v += bias[mth * 32 + mt2 * 16 + l15];
                us4 pk;
                pk[0] = f2bf(v[0]); pk[1] = f2bf(v[1]); pk[2] = f2bf(v[2]); pk[3] = f2bf(v[3]);
                const int c32 = cw * 2 + (ct >> 1);
                const int mt = mth * 2 + mt2;
                const int lanep = ((ct & 1) * 2 + (l4 >> 1)) * 16 + l15;
                *(us4*)(dst + (c32 * 4 + mt) * 1024 + lanep * 16 + (l4 & 1) * 8) = pk;
            }
    }
}

// One batch per block, 4 waves, wave = HEAD (owns all 64 nq rows).
// 256-thread blocks + launch_bounds(256,2): 2 waves/EU -> 2 blocks/CU at a
// 256-reg cap — breaks the 512-thread catch-22 (2 blocks needed (512,4)'s
// 128-reg cap -> spills/serialization, R2..R7). Two independent blocks/CU
// overlap each other's barrier+staging stalls; each weight fragment load now
// feeds 4 MFMAs (was 2) — halves exposed VMEM latency per FLOP.
// LDS 64KB time-multiplexed: q^T frags -> ctx' frags -> Y^T (32KB).
// rule #20: all reg-array subscripts compile-time.
__global__ __launch_bounds__(256, 2)
void lawin_main(const float* __restrict__ query, const float* __restrict__ context,
                const float* __restrict__ pm_b, const float* __restrict__ th_b,
                const float* __restrict__ ph_b, const float* __restrict__ g_b,
                const char* __restrict__ ws, float* __restrict__ out) {
    __shared__ __align__(16) char FR[65536];

    const char* iw  = ws + IW_OFF;
    const char* pmw = ws + PMW_OFF;
    const char* thw = ws + THW_OFF;
    const char* phw = ws + PHW_OFF;
    const char* gww = ws + GW_OFF;
    const char* oww = ws + OUTW_OFF;
    const float* ob = (const float*)(ws + OUTB_OFF);

    const int b = blockIdx.x;
    const int tid = threadIdx.x;
    const int wid = tid >> 6;          // wave = head
    const int lane = tid & 63;
    const int l15 = lane & 15;
    const int l4 = lane >> 4;
    const int h = wid;

    const float* qb = query + (size_t)b * 32768;
    const float* cbp = context + (size_t)b * 32768;
    float* outb = out + (size_t)b * 32768;

    // ---------- T0: q -> q^T frag-array (each wave stages 128 channels) ----------
    stage_T<false>(qb, iw, nullptr, FR, wid * 2, l15, l4);
    stage_T<false>(qb, iw, nullptr, FR, wid * 2 + 1, l15, l4);
    __syncthreads();

    // ---------- T1: Theta[d][nq] (4 d-tiles x 4 nq-tiles), A=thw(L2), B=q^T(LDS) ----------
    short4v thB[4][4];   // [d16-tile][nq16-tile] as S-mfma B-frags
    {
        f32x4 acc[4][4] = {};
        #pragma unroll 2
        for (int ks = 0; ks < 16; ++ks) {
            short8 a[4], bb[4];
            #pragma unroll
            for (int td = 0; td < 4; ++td)
                a[td] = *(const short8*)(thw + (h * 64 + td * 16 + l15) * 1024 + ks * 64 + l4 * 16);
            #pragma unroll
            for (int tb = 0; tb < 4; ++tb)
                bb[tb] = *(const short8*)(FR + (ks * 4 + tb) * 1024 + lane * 16);
            #pragma unroll
            for (int td = 0; td < 4; ++td)
                #pragma unroll
                for (int tb = 0; tb < 4; ++tb)
                    acc[td][tb] = MFMA32(a[td], bb[tb], acc[td][tb]);
        }
        #pragma unroll
        for (int td = 0; td < 4; ++td) {
            f32x4 bv = *(const f32x4*)(th_b + h * 64 + td * 16 + l4 * 4);
            #pragma unroll
            for (int tb = 0; tb < 4; ++tb)
                thB[td][tb] = pack4(acc[td][tb] + bv);
        }
    }
    __syncthreads();   // all waves done reading q^T

    // ---------- T2: posmix (residual folded into W+I) -> ctx' frag-array ----------
    stage_T<true>(cbp, pmw + h * 8192, pm_b + h * 64, FR, wid * 2, l15, l4);
    stage_T<true>(cbp, pmw + h * 8192, pm_b + h * 64, FR, wid * 2 + 1, l15, l4);
    __syncthreads();

    // ---------- T3: Phi -> S^T -> softmax -> pB ----------
    short4v pB[4][4];    // [nc16-tile][nq16-tile] PV A-frags
    {
        f32x4 s_acc[4][4] = {};   // S^T tiles: row=nc(l4*4+r), col=nq(l15)
        #pragma unroll
        for (int dh = 0; dh < 2; ++dh) {          // FULL unroll: indexes thB
            f32x4 pacc[2][4] = {};   // Phi D[d][nc]: [td2][tc]
            #pragma unroll 2
            for (int ks = 0; ks < 16; ++ks) {
                short8 a[2], bb[4];
                #pragma unroll
                for (int td2 = 0; td2 < 2; ++td2)
                    a[td2] = *(const short8*)(phw + (h * 64 + dh * 32 + td2 * 16 + l15) * 1024 + ks * 64 + l4 * 16);
                #pragma unroll
                for (int tc = 0; tc < 4; ++tc)
                    bb[tc] = *(const short8*)(FR + (ks * 4 + tc) * 1024 + lane * 16);
                #pragma unroll
                for (int td2 = 0; td2 < 2; ++td2)
                    #pragma unroll
                    for (int tc = 0; tc < 4; ++tc)
                        pacc[td2][tc] = MFMA32(a[td2], bb[tc], pacc[td2][tc]);
            }
            #pragma unroll
            for (int td2 = 0; td2 < 2; ++td2) {
                f32x4 bv = *(const f32x4*)(ph_b + h * 64 + dh * 32 + td2 * 16 + l4 * 4);
                #pragma unroll
                for (int tc = 0; tc < 4; ++tc) {
                    short4v phB = pack4(pacc[td2][tc] + bv);
                    #pragma unroll
                    for (int tb = 0; tb < 4; ++tb)
                        s_acc[tc][tb] = mfma16(phB, thB[dh * 2 + td2][tb], s_acc[tc][tb]);
                }
            }
        }
        // softmax over nc (per-lane 16 values + shfl over l4), scale 1/8
        #pragma unroll
        for (int tb = 0; tb < 4; ++tb) {
            float mx = -1e30f;
            #pragma unroll
            for (int tc = 0; tc < 4; ++tc)
                #pragma unroll
                for (int r = 0; r < 4; ++r) mx = fmaxf(mx, s_acc[tc][tb][r]);
            mx = fmaxf(mx, __shfl_xor(mx, 16));
            mx = fmaxf(mx, __shfl_xor(mx, 32));
            float sum = 0.f;
            #pragma unroll
            for (int tc = 0; tc < 4; ++tc)
                #pragma unroll
                for (int r = 0; r < 4; ++r) {
                    float v = __expf((s_acc[tc][tb][r] - mx) * 0.125f);
                    s_acc[tc][tb][r] = v;
                    sum += v;
                }
            sum += __shfl_xor(sum, 16);
            sum += __shfl_xor(sum, 32);
            float rinv = 1.0f / sum;
            #pragma unroll
            for (int tc = 0; tc < 4; ++tc)
                pB[tc][tb] = pack4(s_acc[tc][tb] * rinv);
        }
    }

    // ---------- T4: G^T and PV chain -> y_acc ----------
    f32x4 y_acc[4][4] = {};    // [nq-tile][dg16-tile(local)], row=nq, col=dg
    #pragma unroll
    for (int gh = 0; gh < 2; ++gh) {              // FULL unroll: indexes y_acc
        f32x4 gacc[4][2] = {};   // G D[nc][dg]: [tn][tg]
        #pragma unroll 2
        for (int ks = 0; ks < 16; ++ks) {
            short8 a[4], bb[2];
            #pragma unroll
            for (int tn = 0; tn < 4; ++tn)
                a[tn] = *(const short8*)(FR + (ks * 4 + tn) * 1024 + lane * 16);
            #pragma unroll
            for (int tg = 0; tg < 2; ++tg)
                bb[tg] = *(const short8*)(gww + (h * 64 + gh * 32 + tg * 16 + l15) * 1024 + ks * 64 + l4 * 16);
            #pragma unroll
            for (int tn = 0; tn < 4; ++tn)
                #pragma unroll
                for (int tg = 0; tg < 2; ++tg)
                    gacc[tn][tg] = MFMA32(a[tn], bb[tg], gacc[tn][tg]);
        }
        #pragma unroll
        for (int tg = 0; tg < 2; ++tg) {
            float gbv = g_b[h * 64 + gh * 32 + tg * 16 + l15];
            #pragma unroll
            for (int tn = 0; tn < 4; ++tn) {
                short4v gB = pack4(gacc[tn][tg] + gbv);
                #pragma unroll
                for (int tb = 0; tb < 4; ++tb)
                    y_acc[tb][gh * 2 + tg] = mfma16(pB[tn][tb], gB, y_acc[tb][gh * 2 + tg]);
            }
        }
    }
    __syncthreads();   // all waves done reading ctx' frags

    // ---------- Y^T bf16 [64][256] (SW-swizzled) -> FR[0:32K) ----------
    #pragma unroll
    for (int tb = 0; tb < 4; ++tb)
        #pragma unroll
        for (int tdg = 0; tdg < 4; ++tdg)
            #pragma unroll
            for (int r = 0; r < 4; ++r) {
                int nq = tb * 16 + l4 * 4 + r;
                int dg = h * 64 + tdg * 16 + l15;
                *(unsigned short*)(FR + nq * 512 + ((2 * dg) ^ SW(nq))) = f2bf(y_acc[tb][tdg][r]);
            }
    __syncthreads();

    // ---------- T5: out-proj (BN folded) + bias + f32 query residual ----------
    #pragma unroll 1
    for (int och = 0; och < 4; ++och) {    // och only feeds addresses; acc local per iter
        const int ob0 = wid * 128 + och * 32;
        f32x4 acc[4][2] = {};
        #pragma unroll 2
        for (int ks = 0; ks < 8; ++ks) {
            const int kb = ks * 64 + l4 * 16;
            short8 a[4], bb[2];
            #pragma unroll
            for (int tr = 0; tr < 4; ++tr) {
                int tok = tr * 16 + l15;
                a[tr] = *(const short8*)(FR + tok * 512 + (kb ^ SW(tok)));
            }
            #pragma unroll
            for (int oc = 0; oc < 2; ++oc)
                bb[oc] = *(const short8*)(oww + (ob0 + oc * 16 + l15) * 512 + kb);
            #pragma unroll
            for (int tr = 0; tr < 4; ++tr)
                #pragma unroll
                for (int oc = 0; oc < 2; ++oc)
                    acc[tr][oc] = MFMA32(a[tr], bb[oc], acc[tr][oc]);
        }
        #pragma unroll
        for (int oc = 0; oc < 2; ++oc) {
            const int o = ob0 + oc * 16 + l15;
            const float bias = ob[o];
            #pragma unroll
            for (int tr = 0; tr < 4; ++tr) {
                const int tt = tr * 16 + l4 * 4;
                f32x4 qv = *(const f32x4*)(qb + o * 64 + tt);
                f32x4 ov;
                #pragma unroll
                for (int r = 0; r < 4; ++r) ov[r] = acc[tr][oc][r] + bias + qv[r];
                *(f32x4*)(outb + o * 64 + tt) = ov;
            }
        }
    }
}

extern "C" void kernel_launch(void* const* d_in, const int* in_sizes, int n_in,
                              void* d_out, int out_size, void* d_ws, size_t ws_size,
                              hipStream_t stream) {
    const float* query   = (const float*)d_in[0];
    const float* context = (const float*)d_in[1];
    const float* pm_w    = (const float*)d_in[2];
    const float* pm_b    = (const float*)d_in[3];
    const float* g_w     = (const float*)d_in[4];
    const float* g_b     = (const float*)d_in[5];
    const float* th_w    = (const float*)d_in[6];
    const float* th_b    = (const float*)d_in[7];
    const float* ph_w    = (const float*)d_in[8];
    const float* ph_b    = (const float*)d_in[9];
    const float* out_w   = (const float*)d_in[10];
    const float* gamma   = (const float*)d_in[11];
    const float* beta    = (const float*)d_in[12];
    const float* mean    = (const float*)d_in[13];
    const float* var     = (const float*)d_in[14];
    char* ws = (char*)d_ws;
    float* out = (float*)d_out;

    if (ws_size < WS_BYTES) return;

    prep_kernel<<<512, 256, 0, stream>>>(pm_w, g_w, th_w, ph_w, out_w, gamma, beta, mean, var, ws);
    lawin_main<<<NBATCH, 256, 0, stream>>>(query, context, pm_b, th_b, ph_b, g_b, ws, out);
}